// Round 9
// baseline (579.126 us; speedup 1.0000x reference)
//
#include <hip/hip_runtime.h>
#include <math.h>

#define QN 20000
#define PN 80000   // QN*4
#define CN 128
#define NVIEW 6

typedef __attribute__((ext_vector_type(8))) short bf16x8;
typedef __attribute__((ext_vector_type(4))) float f32x4;
typedef __attribute__((ext_vector_type(4))) unsigned short us4;
typedef unsigned short us;

__device__ __forceinline__ us f2bf(float f) {
  unsigned u = __float_as_uint(f);
  return (us)((u + 0x7fffu + ((u >> 16) & 1u)) >> 16);
}
__device__ __forceinline__ float bf2f(us h) {
  return __uint_as_float(((unsigned)h) << 16);
}

__device__ __forceinline__ void gload16(const void* g, void* l) {
  __builtin_amdgcn_global_load_lds(
      (const __attribute__((address_space(1))) void*)g,
      (__attribute__((address_space(3))) void*)l, 16, 0, 0);
}

// ---------------- weight transpose+split: W[K][N] f32 -> T[2][N][Kp] bf16 ----
__global__ __launch_bounds__(256) void wsplit_kernel(const float* __restrict__ W,
                                                     us* __restrict__ Th,
                                                     int K, int N, int Kp) {
  __shared__ float t[32][33];
  us* Tl = Th + (size_t)N * Kp;
  const int n0 = blockIdx.x * 32, k0 = blockIdx.y * 32;
  const int tx = threadIdx.x & 31, ty = threadIdx.x >> 5;  // ty 0..7
  #pragma unroll
  for (int j = 0; j < 4; ++j) {
    int k = k0 + ty + j * 8;
    t[ty + j * 8][tx] = (k < K) ? W[(size_t)k * N + n0 + tx] : 0.f;
  }
  __syncthreads();
  #pragma unroll
  for (int j = 0; j < 4; ++j) {
    int n = n0 + ty + j * 8;
    int k = k0 + tx;
    float v = t[tx][ty + j * 8];
    us h = f2bf(v);
    Th[(size_t)n * Kp + k] = h;
    Tl[(size_t)n * Kp + k] = f2bf(v - bf2f(h));
  }
}

// ---------------- PE input features -> split bf16 planes [2][PN][64] ---------
__global__ __launch_bounds__(256) void pe_in_kernel(const float* __restrict__ rp,
                                                    us* __restrict__ Ph) {
  int idx = blockIdx.x * 256 + threadIdx.x;
  if (idx >= PN * 64) return;
  us* Pl = Ph + (size_t)PN * 64;
  int p = idx >> 6, k = idx & 63;
  float val = 0.f;
  if (k < 60) {
    int q = p >> 2, z = p & 3;
    int d = k / 20, r = k - d * 20;
    int j = (r >= 10) ? (r - 10) : r;
    float pos = rp[((size_t)z * QN + q) * 3 + d];
    float ang = pos * ((float)(1 << j) * 3.14159265358979323846f);
    val = (r >= 10) ? cosf(ang) : sinf(ang);
  }
  us h = f2bf(val);
  Ph[idx] = h;
  Pl[idx] = f2bf(val - bf2f(h));
}

// ---------------- split-bf16 3-term GEMM, single-pass 4-plane staging --------
// Counted-vmcnt pipeline (no full drains):
//   per tile: STAGE(t+1) -> [vmcnt(8)+s_barrier] -> COMPUTE(t) ->
//             [lgkmcnt(0)+s_barrier]
// vmcnt(8) retires exactly tile t's 8 loads (in-order per-wave vmem
// retirement); fused asm blocks with "memory" clobber pin all ordering
// (round-4 failure = unfenced STAGE interleaving).
// OUT=0: f32 C (+bias). OUT=1: split bf16 planes. OUT=2: f32 partial, no bias,
// K split nks ways (Cf + kc*M*N).
template <bool RELU, int OUT>
__global__ __launch_bounds__(256, 2) void gemm3s(const us* __restrict__ Ah,
                                                 const us* __restrict__ Bh,
                                                 const float* __restrict__ bias,
                                                 float* __restrict__ Cf,
                                                 us* __restrict__ Ch,
                                                 int M, int N, int K,
                                                 int nbn, int nks) {
  __shared__ short sm[2][4][4096];  // [buf][Ah,Al,Bh,Bl][128 rows * 32 k]
  const us* __restrict__ Al = Ah + (size_t)M * K;
  const us* __restrict__ Bl = Bh + (size_t)N * K;
  const int tid = threadIdx.x;
  const int wave = tid >> 6, lane = tid & 63;
  const int wr = wave >> 1, wc = wave & 1;
  const int g = lane >> 4, r16 = lane & 15;

  // bijective XCD swizzle (m204)
  const int nwg = gridDim.x;
  const int q8 = nwg >> 3, r8 = nwg & 7;
  const int xcd = blockIdx.x & 7, sub = blockIdx.x >> 3;
  const int wg = (xcd < r8 ? xcd * (q8 + 1) : r8 * (q8 + 1) + (xcd - r8) * q8) + sub;
  const int bn = (wg % nbn) * 128;
  const int rem = wg / nbn;
  const int bm = (rem / nks) * 128;
  const int kc = rem % nks;
  const int kbase = kc * (K / nks);
  const int nt = (K / nks) >> 5;  // K-tiles in this chunk

  f32x4 acc[4][4];
  #pragma unroll
  for (int i = 0; i < 4; ++i)
    #pragma unroll
    for (int j = 0; j < 4; ++j) acc[i][j] = {0.f, 0.f, 0.f, 0.f};

  auto STAGE = [&](int buf, int t) {
    const int kof = kbase + (t << 5);
    const int rsub = lane >> 2;
    const int slot0 = lane & 3;
    #pragma unroll
    for (int pl = 0; pl < 4; ++pl) {
      const us* P = (pl == 0) ? Ah : (pl == 1) ? Al : (pl == 2) ? Bh : Bl;
      const int rbase = (pl < 2) ? bm : bn;
      #pragma unroll
      for (int i = 0; i < 2; ++i) {
        int group = wave * 2 + i;
        int row = group * 16 + rsub;
        int slot = slot0 ^ ((row >> 1) & 3);
        int gr = rbase + row;
        if (pl < 2 && gr >= M) gr = M - 1;
        gload16(P + (size_t)gr * K + kof + slot * 8,
                &sm[buf][pl][group * 512]);
      }
    }
  };

  auto COMPUTE = [&](int buf) {
    bf16x8 ah[4], al[4], bh[4], bl[4];
    #pragma unroll
    for (int mi = 0; mi < 4; ++mi) {
      int row = wr * 64 + mi * 16 + r16;
      int off = row * 32 + ((g ^ ((row >> 1) & 3)) * 8);
      ah[mi] = *(const bf16x8*)&sm[buf][0][off];
      al[mi] = *(const bf16x8*)&sm[buf][1][off];
    }
    #pragma unroll
    for (int ni = 0; ni < 4; ++ni) {
      int row = wc * 64 + ni * 16 + r16;
      int off = row * 32 + ((g ^ ((row >> 1) & 3)) * 8);
      bh[ni] = *(const bf16x8*)&sm[buf][2][off];
      bl[ni] = *(const bf16x8*)&sm[buf][3][off];
    }
    #pragma unroll
    for (int mi = 0; mi < 4; ++mi)
      #pragma unroll
      for (int ni = 0; ni < 4; ++ni)
        acc[mi][ni] = __builtin_amdgcn_mfma_f32_16x16x32_bf16(ah[mi], bh[ni], acc[mi][ni], 0, 0, 0);
    #pragma unroll
    for (int mi = 0; mi < 4; ++mi)
      #pragma unroll
      for (int ni = 0; ni < 4; ++ni)
        acc[mi][ni] = __builtin_amdgcn_mfma_f32_16x16x32_bf16(al[mi], bh[ni], acc[mi][ni], 0, 0, 0);
    #pragma unroll
    for (int mi = 0; mi < 4; ++mi)
      #pragma unroll
      for (int ni = 0; ni < 4; ++ni)
        acc[mi][ni] = __builtin_amdgcn_mfma_f32_16x16x32_bf16(ah[mi], bl[ni], acc[mi][ni], 0, 0, 0);
  };

  STAGE(0, 0);
  asm volatile("" ::: "memory");  // pin issue order vs loop's STAGE(1)

  for (int t = 0; t < nt; ++t) {
    const int cur = t & 1;
    if (t + 1 < nt) {
      STAGE(cur ^ 1, t + 1);
      asm volatile("" ::: "memory");
      // wait tile t's 8 loads (oldest; t+1's 8 stay in flight), then barrier
      asm volatile("s_waitcnt vmcnt(8)\n\ts_barrier" ::: "memory");
    } else {
      asm volatile("s_waitcnt vmcnt(0)\n\ts_barrier" ::: "memory");
    }
    COMPUTE(cur);
    // WAR fence: my LDS reads done, then all-waves barrier (no vmcnt drain)
    asm volatile("s_waitcnt lgkmcnt(0)\n\ts_barrier" ::: "memory");
  }

  us* Cl = Ch + (size_t)M * N;
  #pragma unroll
  for (int mi = 0; mi < 4; ++mi) {
    int gr0 = bm + wr * 64 + mi * 16 + (lane >> 4) * 4;
    #pragma unroll
    for (int ni = 0; ni < 4; ++ni) {
      int gc = bn + wc * 64 + ni * 16 + r16;
      float bv = (OUT == 2) ? 0.f : bias[gc];
      #pragma unroll
      for (int r = 0; r < 4; ++r) {
        int row = gr0 + r;
        if (row >= M) continue;
        float v = acc[mi][ni][r] + bv;
        if (RELU) v = fmaxf(v, 0.f);
        if (OUT == 0) {
          Cf[(size_t)row * N + gc] = v;
        } else if (OUT == 2) {
          Cf[(size_t)kc * M * N + (size_t)row * N + gc] = v;
        } else {
          us h = f2bf(v);
          Ch[(size_t)row * N + gc] = h;
          Cl[(size_t)row * N + gc] = f2bf(v - bf2f(h));
        }
      }
    }
  }
}

// ---------------- K-split reduce: out = sum_kc partial[kc] + bias ------------
__global__ __launch_bounds__(256) void kreduce_kernel(const float* __restrict__ part,
                                                      const float* __restrict__ bias,
                                                      float* __restrict__ out) {
  int i = blockIdx.x * 256 + threadIdx.x;        // over QN*CN/4
  if (i >= QN * (CN / 4)) return;
  int col4 = (i & 31) * 4;
  const size_t stride = (size_t)QN * CN;
  f32x4 s = *(const f32x4*)(part + (size_t)i * 4);
  s += *(const f32x4*)(part + stride + (size_t)i * 4);
  s += *(const f32x4*)(part + 2 * stride + (size_t)i * 4);
  s += *(const f32x4*)(part + 3 * stride + (size_t)i * 4);
  s += *(const f32x4*)(bias + col4);
  *(f32x4*)(out + (size_t)i * 4) = s;
}

// ---------------- fused softmax + projection + bilinear sample --------------
// 2 points per wave (unchanged from round 8 -- verified off the critical list)
__global__ __launch_bounds__(256) void sample_kernel(
    const float* __restrict__ f0, const float* __restrict__ f1,
    const float* __restrict__ f2, const float* __restrict__ f3,
    const float* __restrict__ rp, const float* __restrict__ l2i,
    const float* __restrict__ wtw, const float* __restrict__ wtb,
    const float* __restrict__ posE, us* __restrict__ X0h) {
  __shared__ float sl2i[96];
  __shared__ float swtT[512];  // transposed [4][128]
  __shared__ float sb[4];
  const int tid = threadIdx.x;
  if (tid < 96) sl2i[tid] = l2i[tid];
  for (int i = tid; i < 512; i += 256) swtT[(i & 3) * 128 + (i >> 2)] = wtw[i];
  if (tid < 4) sb[tid] = wtb[tid];
  __syncthreads();

  us* X0l = X0h + (size_t)QN * 512;
  const int wave = tid >> 6, lane = tid & 63;
  const int half = lane >> 5, s = lane & 31;
  const int p = blockIdx.x * 8 + wave * 2 + half;
  const int q = p >> 2, z = p & 3;

  const float X  = rp[((size_t)z * QN + q) * 3 + 0] * 100.f - 50.f;
  const float Y  = rp[((size_t)z * QN + q) * 3 + 1] * 100.f - 50.f;
  const float Zc = rp[((size_t)z * QN + q) * 3 + 2] * 8.f - 4.f;

  const int c0 = s * 4;
  f32x4 pe = *(const f32x4*)(posE + (size_t)p * CN + c0);

  float l0 = pe[0] * swtT[0 * 128 + c0] + pe[1] * swtT[0 * 128 + c0 + 1]
           + pe[2] * swtT[0 * 128 + c0 + 2] + pe[3] * swtT[0 * 128 + c0 + 3];
  float l1 = pe[0] * swtT[1 * 128 + c0] + pe[1] * swtT[1 * 128 + c0 + 1]
           + pe[2] * swtT[1 * 128 + c0 + 2] + pe[3] * swtT[1 * 128 + c0 + 3];
  float l2 = pe[0] * swtT[2 * 128 + c0] + pe[1] * swtT[2 * 128 + c0 + 1]
           + pe[2] * swtT[2 * 128 + c0 + 2] + pe[3] * swtT[2 * 128 + c0 + 3];
  float l3 = pe[0] * swtT[3 * 128 + c0] + pe[1] * swtT[3 * 128 + c0 + 1]
           + pe[2] * swtT[3 * 128 + c0 + 2] + pe[3] * swtT[3 * 128 + c0 + 3];
  #pragma unroll
  for (int off = 16; off > 0; off >>= 1) {
    l0 += __shfl_xor(l0, off);
    l1 += __shfl_xor(l1, off);
    l2 += __shfl_xor(l2, off);
    l3 += __shfl_xor(l3, off);
  }
  l0 += sb[0]; l1 += sb[1]; l2 += sb[2]; l3 += sb[3];
  float mx = fmaxf(fmaxf(l0, l1), fmaxf(l2, l3));
  float ex0 = __expf(l0 - mx), ex1 = __expf(l1 - mx);
  float ex2 = __expf(l2 - mx), ex3 = __expf(l3 - mx);
  float esr = 1.f / (ex0 + ex1 + ex2 + ex3);
  float swl[4] = {ex0 * esr, ex1 * esr, ex2 * esr, ex3 * esr};

  const float* FT[4] = {f0, f1, f2, f3};

  float a0 = 0.f, a1 = 0.f, a2 = 0.f, a3 = 0.f;
  for (int n = 0; n < NVIEW; n++) {
    const float* Mx = sl2i + n * 16;
    float cam0 = Mx[0] * X + Mx[1] * Y + Mx[2]  * Zc + Mx[3];
    float cam1 = Mx[4] * X + Mx[5] * Y + Mx[6]  * Zc + Mx[7];
    float cam2 = Mx[8] * X + Mx[9] * Y + Mx[10] * Zc + Mx[11];
    float denom = fmaxf(cam2, 1e-5f);
    float u = cam0 / denom * (1.f / 704.f);
    float v = cam1 / denom * (1.f / 256.f);
    bool valid = (cam2 > 1e-5f) & (u > 0.f) & (u < 1.f) & (v > 0.f) & (v < 1.f);
    if (valid) {
      #pragma unroll
      for (int l = 0; l < 4; l++) {
        const int Hl = 64 >> l, Wl = 176 >> l;
        float pxl = u * (float)Wl - 0.5f;
        float pyl = v * (float)Hl - 0.5f;
        float fx = floorf(pxl), fy = floorf(pyl);
        int x0 = (int)fx, y0 = (int)fy;
        float wx = pxl - fx, wy = pyl - fy;
        const float wxs[2] = {1.f - wx, wx};
        const float wys[2] = {1.f - wy, wy};
        const float* fb = FT[l] + (size_t)n * (Hl * Wl * CN);
        #pragma unroll
        for (int cy = 0; cy < 2; cy++) {
          #pragma unroll
          for (int cx = 0; cx < 2; cx++) {
            int xi = x0 + cx, yi = y0 + cy;
            bool inb = ((unsigned)xi < (unsigned)Wl) & ((unsigned)yi < (unsigned)Hl);
            int off = inb ? (yi * Wl + xi) * CN : 0;
            float wgt = inb ? (wys[cy] * wxs[cx] * swl[l]) : 0.f;
            f32x4 vv = *(const f32x4*)(fb + off + c0);
            a0 = fmaf(wgt, vv[0], a0);
            a1 = fmaf(wgt, vv[1], a1);
            a2 = fmaf(wgt, vv[2], a2);
            a3 = fmaf(wgt, vv[3], a3);
          }
        }
      }
    }
  }
  float o0 = a0 + pe[0], o1 = a1 + pe[1], o2 = a2 + pe[2], o3 = a3 + pe[3];
  size_t base = (size_t)p * CN + c0;
  us4 hi, lo;
  hi[0] = f2bf(o0); lo[0] = f2bf(o0 - bf2f(hi[0]));
  hi[1] = f2bf(o1); lo[1] = f2bf(o1 - bf2f(hi[1]));
  hi[2] = f2bf(o2); lo[2] = f2bf(o2 - bf2f(hi[2]));
  hi[3] = f2bf(o3); lo[3] = f2bf(o3 - bf2f(hi[3]));
  *(us4*)&X0h[base] = hi;
  *(us4*)&X0l[base] = lo;
}

extern "C" void kernel_launch(void* const* d_in, const int* in_sizes, int n_in,
                              void* d_out, int out_size, void* d_ws, size_t ws_size,
                              hipStream_t stream) {
  const float* feat0 = (const float*)d_in[0];
  const float* feat1 = (const float*)d_in[1];
  const float* feat2 = (const float*)d_in[2];
  const float* feat3 = (const float*)d_in[3];
  const float* rp    = (const float*)d_in[4];
  const float* l2i   = (const float*)d_in[5];
  const float* pe_w1 = (const float*)d_in[6];
  const float* pe_b1 = (const float*)d_in[7];
  const float* pe_w2 = (const float*)d_in[8];
  const float* pe_b2 = (const float*)d_in[9];
  const float* wt_w  = (const float*)d_in[10];
  const float* wt_b  = (const float*)d_in[11];
  const float* hm_w1 = (const float*)d_in[12];
  const float* hm_b1 = (const float*)d_in[13];
  const float* hm_w2 = (const float*)d_in[14];
  const float* hm_b2 = (const float*)d_in[15];
  const float* hm_w3 = (const float*)d_in[16];
  const float* hm_b3 = (const float*)d_in[17];
  const float* hm_w4 = (const float*)d_in[18];
  const float* hm_b4 = (const float*)d_in[19];
  float* out = (float*)d_out;

  char* ws = (char*)d_ws;
  // weights: [2][N][Kp] split planes
  us* wPE1 = (us*)(ws + 0);         // 2*256*64   = 65536 B
  us* wPE2 = (us*)(ws + 65536);     // 2*128*256  = 131072 B
  us* wH1  = (us*)(ws + 196608);    // 2*1024*512 = 2097152 B
  us* wH2  = (us*)(ws + 2293760);   // 2*1024*1024= 4194304 B
  us* wH3  = (us*)(ws + 6488064);   // 4194304 B
  us* wH4  = (us*)(ws + 10682368);  // 2*128*1024 = 524288 B -> end 11206656

  // activations (liveness-aliased, peak 175.9 MB)
  float* posE = (float*)(ws + 11534336);   // [80000][128] f32, end 52.49M
  us*    hpe  = (us*)(ws + 53000192);      // [2][80000][256], end 134.92M
  us*    pein = (us*)(ws + 135000064);     // [2][80000][64],  end 155.48M
  us*    X0   = (us*)(ws + 53000192);      // [2][20000][512]  (hpe dead), end 93.96M
  us*    H1   = (us*)(ws + 94000128);      // [2][20000][1024], end 175.92M
  us*    H2   = (us*)(ws + 11534336);      // (posE/X0 dead), end 93.45M
  us*    H3   = (us*)(ws + 94000128);      // (H1 dead), end 175.92M
  float* part = (float*)(ws + 11534336);   // [4][20000][128] f32 (H2 dead), 41 MB

  // 0. weight transpose+split
  wsplit_kernel<<<dim3(8, 2),   256, 0, stream>>>(pe_w1, wPE1, 60,   256,  64);
  wsplit_kernel<<<dim3(4, 8),   256, 0, stream>>>(pe_w2, wPE2, 256,  128,  256);
  wsplit_kernel<<<dim3(32, 16), 256, 0, stream>>>(hm_w1, wH1,  512,  1024, 512);
  wsplit_kernel<<<dim3(32, 32), 256, 0, stream>>>(hm_w2, wH2,  1024, 1024, 1024);
  wsplit_kernel<<<dim3(32, 32), 256, 0, stream>>>(hm_w3, wH3,  1024, 1024, 1024);
  wsplit_kernel<<<dim3(4, 32),  256, 0, stream>>>(hm_w4, wH4,  1024, 128,  1024);

  // 1. PE features (split planes, K padded 60->64)
  pe_in_kernel<<<(PN * 64 + 255) / 256, 256, 0, stream>>>(rp, pein);

  // 2. PE MLP: 64 -> 256 (relu) -> 128 (f32 posE)
  gemm3s<true, 1><<<2 * 625, 256, 0, stream>>>(pein, wPE1, pe_b1, nullptr, hpe, PN, 256, 64, 2, 1);
  gemm3s<false, 0><<<1 * 625, 256, 0, stream>>>(hpe, wPE2, pe_b2, posE, nullptr, PN, 128, 256, 1, 1);

  // 3. fused softmax + projection + sampling -> X0 split planes
  sample_kernel<<<PN / 8, 256, 0, stream>>>(feat0, feat1, feat2, feat3, rp, l2i,
                                            wt_w, wt_b, posE, X0);

  // 4. head MLP: 512 -> 1024 -> 1024 -> 1024 -> 128 (last layer K-split x4)
  gemm3s<true, 1><<<8 * 157, 256, 0, stream>>>(X0, wH1, hm_b1, nullptr, H1, QN, 1024, 512, 8, 1);
  gemm3s<true, 1><<<8 * 157, 256, 0, stream>>>(H1, wH2, hm_b2, nullptr, H2, QN, 1024, 1024, 8, 1);
  gemm3s<true, 1><<<8 * 157, 256, 0, stream>>>(H2, wH3, hm_b3, nullptr, H3, QN, 1024, 1024, 8, 1);
  gemm3s<false, 2><<<4 * 157, 256, 0, stream>>>(H3, wH4, nullptr, part, nullptr, QN, 128, 1024, 1, 4);
  kreduce_kernel<<<(QN * (CN / 4) + 255) / 256, 256, 0, stream>>>(part, hm_b4, out);
}

// Round 10
// 331.166 us; speedup vs baseline: 1.7487x; 1.7487x over previous
//
#include <hip/hip_runtime.h>
#include <math.h>

#define QN 20000
#define PN 80000   // QN*4
#define CN 128
#define NVIEW 6

typedef __attribute__((ext_vector_type(8))) _Float16 h8;
typedef __attribute__((ext_vector_type(4))) _Float16 h4;
typedef __attribute__((ext_vector_type(4))) float f32x4;

__device__ __forceinline__ void gload16(const void* g, void* l) {
  __builtin_amdgcn_global_load_lds(
      (const __attribute__((address_space(1))) void*)g,
      (__attribute__((address_space(3))) void*)l, 16, 0, 0);
}

// ---------------- weight transpose: W[K][N] f32 -> T[N][Kp] f16 (K zero-pad) --
__global__ __launch_bounds__(256) void wtrans_kernel(const float* __restrict__ W,
                                                     _Float16* __restrict__ T,
                                                     int K, int N, int Kp) {
  __shared__ float t[32][33];
  const int n0 = blockIdx.x * 32, k0 = blockIdx.y * 32;
  const int tx = threadIdx.x & 31, ty = threadIdx.x >> 5;  // ty 0..7
  #pragma unroll
  for (int j = 0; j < 4; ++j) {
    int k = k0 + ty + j * 8;
    t[ty + j * 8][tx] = (k < K) ? W[(size_t)k * N + n0 + tx] : 0.f;
  }
  __syncthreads();
  #pragma unroll
  for (int j = 0; j < 4; ++j) {
    int n = n0 + ty + j * 8;
    int k = k0 + tx;
    T[(size_t)n * Kp + k] = (_Float16)t[tx][ty + j * 8];
  }
}

// ---------------- PE input features: sin/cos -> f16 [PN][64] -----------------
__global__ __launch_bounds__(256) void pe_in_kernel(const float* __restrict__ rp,
                                                    _Float16* __restrict__ P) {
  int idx = blockIdx.x * 256 + threadIdx.x;
  if (idx >= PN * 64) return;
  int p = idx >> 6, k = idx & 63;
  float val = 0.f;
  if (k < 60) {
    int q = p >> 2, z = p & 3;
    int d = k / 20, r = k - d * 20;
    int j = (r >= 10) ? (r - 10) : r;
    float pos = rp[((size_t)z * QN + q) * 3 + d];
    float ang = pos * ((float)(1 << j) * 3.14159265358979323846f);
    val = (r >= 10) ? cosf(ang) : sinf(ang);
  }
  P[idx] = (_Float16)val;
}

// ---------------- fp16 MFMA GEMM: C = A[MxK] @ B^T[NxK] (+bias) --------------
// 128x128 tile, BK=32, 256 thr (2x2 waves, 64x64/wave). 2-plane staging
// (A,B f16) = 16KB/buf, dbuf 32KB -> 4 blocks/CU (16 waves, 4/SIMD).
// Proven 2-phase pipeline: STAGE(t+1) issued before COMPUTE(t), one
// __syncthreads per tile. XCD-aware bijective block swizzle (m204).
// LDS anti-conflict: slot ^= (row>>1)&3 involution on source & read.
// OUT=0: f32 C (+bias). OUT=1: f16 C (+bias). OUT=2: f32 partial, no bias,
// K split nks ways (Cf + kc*M*N).
template <bool RELU, int OUT>
__global__ __launch_bounds__(256, 4) void gemm_h(const _Float16* __restrict__ A,
                                                 const _Float16* __restrict__ B,
                                                 const float* __restrict__ bias,
                                                 float* __restrict__ Cf,
                                                 _Float16* __restrict__ Ch,
                                                 int M, int N, int K,
                                                 int nbn, int nks) {
  __shared__ _Float16 sm[2][2][4096];  // [buf][A,B][128 rows * 32 k]
  const int tid = threadIdx.x;
  const int wave = tid >> 6, lane = tid & 63;
  const int wr = wave >> 1, wc = wave & 1;
  const int g = lane >> 4, r16 = lane & 15;

  // bijective XCD swizzle (m204)
  const int nwg = gridDim.x;
  const int q8 = nwg >> 3, r8 = nwg & 7;
  const int xcd = blockIdx.x & 7, sub = blockIdx.x >> 3;
  const int wg = (xcd < r8 ? xcd * (q8 + 1) : r8 * (q8 + 1) + (xcd - r8) * q8) + sub;
  const int bn = (wg % nbn) * 128;
  const int rem = wg / nbn;
  const int bm = (rem / nks) * 128;
  const int kc = rem % nks;
  const int kbase = kc * (K / nks);
  const int nt = (K / nks) >> 5;  // K-tiles in this chunk

  f32x4 acc[4][4];
  #pragma unroll
  for (int i = 0; i < 4; ++i)
    #pragma unroll
    for (int j = 0; j < 4; ++j) acc[i][j] = {0.f, 0.f, 0.f, 0.f};

  // stage one K-tile: 2 planes x 128 rows x 32 k (8KB/plane), 4 instr/wave
  auto STAGE = [&](int buf, int t) {
    const int kof = kbase + (t << 5);
    const int rsub = lane >> 2;                    // 0..15
    const int slot0 = lane & 3;
    #pragma unroll
    for (int pl = 0; pl < 2; ++pl) {
      const _Float16* P = (pl == 0) ? A : B;
      const int rbase = (pl == 0) ? bm : bn;
      #pragma unroll
      for (int i = 0; i < 2; ++i) {
        int group = wave * 2 + i;                  // 0..7
        int row = group * 16 + rsub;               // 0..127
        int slot = slot0 ^ ((row >> 1) & 3);       // pre-swizzled source
        int gr = rbase + row;
        if (pl == 0 && gr >= M) gr = M - 1;
        gload16(P + (size_t)gr * K + kof + slot * 8,
                &sm[buf][pl][group * 512]);        // linear LDS dest
      }
    }
  };

  auto COMPUTE = [&](int buf) {
    h8 a[4], b[4];
    #pragma unroll
    for (int mi = 0; mi < 4; ++mi) {
      int row = wr * 64 + mi * 16 + r16;
      int off = row * 32 + ((g ^ ((row >> 1) & 3)) * 8);  // swizzled read
      a[mi] = *(const h8*)&sm[buf][0][off];
    }
    #pragma unroll
    for (int ni = 0; ni < 4; ++ni) {
      int row = wc * 64 + ni * 16 + r16;
      int off = row * 32 + ((g ^ ((row >> 1) & 3)) * 8);
      b[ni] = *(const h8*)&sm[buf][1][off];
    }
    #pragma unroll
    for (int mi = 0; mi < 4; ++mi)
      #pragma unroll
      for (int ni = 0; ni < 4; ++ni)
        acc[mi][ni] = __builtin_amdgcn_mfma_f32_16x16x32_f16(a[mi], b[ni], acc[mi][ni], 0, 0, 0);
  };

  STAGE(0, 0);
  __syncthreads();                 // vmcnt(0)+lgkmcnt(0)+barrier

  for (int t = 0; t < nt; ++t) {
    if (t + 1 < nt) STAGE((t + 1) & 1, t + 1);  // prefetch next (issue only)
    COMPUTE(t & 1);                             // 16 MFMA overlap the loads
    __syncthreads();               // drain prefetch + WAR fence, once per tile
  }

  // epilogue: D row = (lane>>4)*4 + r, col = lane&15 within each 16x16 frag
  #pragma unroll
  for (int mi = 0; mi < 4; ++mi) {
    int gr0 = bm + wr * 64 + mi * 16 + (lane >> 4) * 4;
    #pragma unroll
    for (int ni = 0; ni < 4; ++ni) {
      int gc = bn + wc * 64 + ni * 16 + r16;
      float bv = (OUT == 2) ? 0.f : bias[gc];
      #pragma unroll
      for (int r = 0; r < 4; ++r) {
        int row = gr0 + r;
        if (row >= M) continue;
        float v = acc[mi][ni][r] + bv;
        if (RELU) v = fmaxf(v, 0.f);
        if (OUT == 0) {
          Cf[(size_t)row * N + gc] = v;
        } else if (OUT == 2) {
          Cf[(size_t)kc * M * N + (size_t)row * N + gc] = v;
        } else {
          Ch[(size_t)row * N + gc] = (_Float16)v;
        }
      }
    }
  }
}

// ---------------- K-split reduce: out = sum_kc partial[kc] + bias ------------
__global__ __launch_bounds__(256) void kreduce_kernel(const float* __restrict__ part,
                                                      const float* __restrict__ bias,
                                                      float* __restrict__ out) {
  int i = blockIdx.x * 256 + threadIdx.x;        // over QN*CN/4
  if (i >= QN * (CN / 4)) return;
  int col4 = (i & 31) * 4;
  const size_t stride = (size_t)QN * CN;
  f32x4 s = *(const f32x4*)(part + (size_t)i * 4);
  s += *(const f32x4*)(part + stride + (size_t)i * 4);
  s += *(const f32x4*)(part + 2 * stride + (size_t)i * 4);
  s += *(const f32x4*)(part + 3 * stride + (size_t)i * 4);
  s += *(const f32x4*)(bias + col4);
  *(f32x4*)(out + (size_t)i * 4) = s;
}

// ---------------- fused softmax + projection + bilinear sample --------------
// 2 points per wave (r8-proven); X0 written as single f16 plane.
__global__ __launch_bounds__(256) void sample_kernel(
    const float* __restrict__ f0, const float* __restrict__ f1,
    const float* __restrict__ f2, const float* __restrict__ f3,
    const float* __restrict__ rp, const float* __restrict__ l2i,
    const float* __restrict__ wtw, const float* __restrict__ wtb,
    const float* __restrict__ posE, _Float16* __restrict__ X0) {
  __shared__ float sl2i[96];
  __shared__ float swtT[512];  // transposed [4][128]
  __shared__ float sb[4];
  const int tid = threadIdx.x;
  if (tid < 96) sl2i[tid] = l2i[tid];
  for (int i = tid; i < 512; i += 256) swtT[(i & 3) * 128 + (i >> 2)] = wtw[i];
  if (tid < 4) sb[tid] = wtb[tid];
  __syncthreads();

  const int wave = tid >> 6, lane = tid & 63;
  const int half = lane >> 5, s = lane & 31;
  const int p = blockIdx.x * 8 + wave * 2 + half;
  const int q = p >> 2, z = p & 3;

  const float X  = rp[((size_t)z * QN + q) * 3 + 0] * 100.f - 50.f;
  const float Y  = rp[((size_t)z * QN + q) * 3 + 1] * 100.f - 50.f;
  const float Zc = rp[((size_t)z * QN + q) * 3 + 2] * 8.f - 4.f;

  const int c0 = s * 4;
  f32x4 pe = *(const f32x4*)(posE + (size_t)p * CN + c0);

  float l0 = pe[0] * swtT[0 * 128 + c0] + pe[1] * swtT[0 * 128 + c0 + 1]
           + pe[2] * swtT[0 * 128 + c0 + 2] + pe[3] * swtT[0 * 128 + c0 + 3];
  float l1 = pe[0] * swtT[1 * 128 + c0] + pe[1] * swtT[1 * 128 + c0 + 1]
           + pe[2] * swtT[1 * 128 + c0 + 2] + pe[3] * swtT[1 * 128 + c0 + 3];
  float l2 = pe[0] * swtT[2 * 128 + c0] + pe[1] * swtT[2 * 128 + c0 + 1]
           + pe[2] * swtT[2 * 128 + c0 + 2] + pe[3] * swtT[2 * 128 + c0 + 3];
  float l3 = pe[0] * swtT[3 * 128 + c0] + pe[1] * swtT[3 * 128 + c0 + 1]
           + pe[2] * swtT[3 * 128 + c0 + 2] + pe[3] * swtT[3 * 128 + c0 + 3];
  #pragma unroll
  for (int off = 16; off > 0; off >>= 1) {
    l0 += __shfl_xor(l0, off);
    l1 += __shfl_xor(l1, off);
    l2 += __shfl_xor(l2, off);
    l3 += __shfl_xor(l3, off);
  }
  l0 += sb[0]; l1 += sb[1]; l2 += sb[2]; l3 += sb[3];
  float mx = fmaxf(fmaxf(l0, l1), fmaxf(l2, l3));
  float ex0 = __expf(l0 - mx), ex1 = __expf(l1 - mx);
  float ex2 = __expf(l2 - mx), ex3 = __expf(l3 - mx);
  float esr = 1.f / (ex0 + ex1 + ex2 + ex3);
  float swl[4] = {ex0 * esr, ex1 * esr, ex2 * esr, ex3 * esr};

  const float* FT[4] = {f0, f1, f2, f3};

  float a0 = 0.f, a1 = 0.f, a2 = 0.f, a3 = 0.f;
  for (int n = 0; n < NVIEW; n++) {
    const float* Mx = sl2i + n * 16;
    float cam0 = Mx[0] * X + Mx[1] * Y + Mx[2]  * Zc + Mx[3];
    float cam1 = Mx[4] * X + Mx[5] * Y + Mx[6]  * Zc + Mx[7];
    float cam2 = Mx[8] * X + Mx[9] * Y + Mx[10] * Zc + Mx[11];
    float denom = fmaxf(cam2, 1e-5f);
    float u = cam0 / denom * (1.f / 704.f);
    float v = cam1 / denom * (1.f / 256.f);
    bool valid = (cam2 > 1e-5f) & (u > 0.f) & (u < 1.f) & (v > 0.f) & (v < 1.f);
    if (valid) {
      #pragma unroll
      for (int l = 0; l < 4; l++) {
        const int Hl = 64 >> l, Wl = 176 >> l;
        float pxl = u * (float)Wl - 0.5f;
        float pyl = v * (float)Hl - 0.5f;
        float fx = floorf(pxl), fy = floorf(pyl);
        int x0 = (int)fx, y0 = (int)fy;
        float wx = pxl - fx, wy = pyl - fy;
        const float wxs[2] = {1.f - wx, wx};
        const float wys[2] = {1.f - wy, wy};
        const float* fb = FT[l] + (size_t)n * (Hl * Wl * CN);
        #pragma unroll
        for (int cy = 0; cy < 2; cy++) {
          #pragma unroll
          for (int cx = 0; cx < 2; cx++) {
            int xi = x0 + cx, yi = y0 + cy;
            bool inb = ((unsigned)xi < (unsigned)Wl) & ((unsigned)yi < (unsigned)Hl);
            int off = inb ? (yi * Wl + xi) * CN : 0;
            float wgt = inb ? (wys[cy] * wxs[cx] * swl[l]) : 0.f;
            f32x4 vv = *(const f32x4*)(fb + off + c0);
            a0 = fmaf(wgt, vv[0], a0);
            a1 = fmaf(wgt, vv[1], a1);
            a2 = fmaf(wgt, vv[2], a2);
            a3 = fmaf(wgt, vv[3], a3);
          }
        }
      }
    }
  }
  h4 o;
  o[0] = (_Float16)(a0 + pe[0]);
  o[1] = (_Float16)(a1 + pe[1]);
  o[2] = (_Float16)(a2 + pe[2]);
  o[3] = (_Float16)(a3 + pe[3]);
  *(h4*)&X0[(size_t)p * CN + c0] = o;  // row q, col z*128+c0
}

extern "C" void kernel_launch(void* const* d_in, const int* in_sizes, int n_in,
                              void* d_out, int out_size, void* d_ws, size_t ws_size,
                              hipStream_t stream) {
  const float* feat0 = (const float*)d_in[0];
  const float* feat1 = (const float*)d_in[1];
  const float* feat2 = (const float*)d_in[2];
  const float* feat3 = (const float*)d_in[3];
  const float* rp    = (const float*)d_in[4];
  const float* l2i   = (const float*)d_in[5];
  const float* pe_w1 = (const float*)d_in[6];
  const float* pe_b1 = (const float*)d_in[7];
  const float* pe_w2 = (const float*)d_in[8];
  const float* pe_b2 = (const float*)d_in[9];
  const float* wt_w  = (const float*)d_in[10];
  const float* wt_b  = (const float*)d_in[11];
  const float* hm_w1 = (const float*)d_in[12];
  const float* hm_b1 = (const float*)d_in[13];
  const float* hm_w2 = (const float*)d_in[14];
  const float* hm_b2 = (const float*)d_in[15];
  const float* hm_w3 = (const float*)d_in[16];
  const float* hm_b3 = (const float*)d_in[17];
  const float* hm_w4 = (const float*)d_in[18];
  const float* hm_b4 = (const float*)d_in[19];
  float* out = (float*)d_out;

  char* ws = (char*)d_ws;
  typedef _Float16 h16;
  // weights: transposed f16 [N][Kp]
  h16* wPE1 = (h16*)(ws + 0);         // 256x64   = 32768 B
  h16* wPE2 = (h16*)(ws + 65536);     // 128x256  = 65536 B
  h16* wH1  = (h16*)(ws + 196608);    // 1024x512 = 1 MB
  h16* wH2  = (h16*)(ws + 2293760);   // 1024x1024= 2 MB
  h16* wH3  = (h16*)(ws + 6488064);   // 2 MB
  h16* wH4  = (h16*)(ws + 10682368);  // 128x1024 = 256 KB

  // activations (liveness-aliased, peak ~135 MB)
  float* posE = (float*)(ws + 11534336);   // [80000][128] f32, end 52.5M
  h16*   hpe  = (h16*)(ws + 53000192);     // [80000][256] f16, end 94.0M
  h16*   pein = (h16*)(ws + 94000128);     // [80000][64] f16,  end 104.2M
  h16*   X0   = (h16*)(ws + 53000192);     // [20000][512] f16 (hpe dead)
  h16*   H1   = (h16*)(ws + 94000128);     // [20000][1024] f16 (pein dead), end 135M
  h16*   H2   = (h16*)(ws + 11534336);     // (posE dead after sample), end 52.5M
  h16*   H3   = (h16*)(ws + 94000128);     // (H1 dead)
  float* part = (float*)(ws + 11534336);   // [4][20000][128] f32 (H2 dead), 41 MB

  // 0. weight transpose -> f16
  wtrans_kernel<<<dim3(8, 2),   256, 0, stream>>>(pe_w1, wPE1, 60,   256,  64);
  wtrans_kernel<<<dim3(4, 8),   256, 0, stream>>>(pe_w2, wPE2, 256,  128,  256);
  wtrans_kernel<<<dim3(32, 16), 256, 0, stream>>>(hm_w1, wH1,  512,  1024, 512);
  wtrans_kernel<<<dim3(32, 32), 256, 0, stream>>>(hm_w2, wH2,  1024, 1024, 1024);
  wtrans_kernel<<<dim3(32, 32), 256, 0, stream>>>(hm_w3, wH3,  1024, 1024, 1024);
  wtrans_kernel<<<dim3(4, 32),  256, 0, stream>>>(hm_w4, wH4,  1024, 128,  1024);

  // 1. PE features (f16, K padded 60->64)
  pe_in_kernel<<<(PN * 64 + 255) / 256, 256, 0, stream>>>(rp, pein);

  // 2. PE MLP: 64 -> 256 (relu) -> 128 (f32 posE)
  gemm_h<true, 1><<<2 * 625, 256, 0, stream>>>(pein, wPE1, pe_b1, nullptr, hpe, PN, 256, 64, 2, 1);
  gemm_h<false, 0><<<1 * 625, 256, 0, stream>>>(hpe, wPE2, pe_b2, posE, nullptr, PN, 128, 256, 1, 1);

  // 3. fused softmax + projection + sampling -> X0 f16
  sample_kernel<<<PN / 8, 256, 0, stream>>>(feat0, feat1, feat2, feat3, rp, l2i,
                                            wt_w, wt_b, posE, X0);

  // 4. head MLP: 512 -> 1024 -> 1024 -> 1024 -> 128 (last layer K-split x4)
  gemm_h<true, 1><<<8 * 157, 256, 0, stream>>>(X0, wH1, hm_b1, nullptr, H1, QN, 1024, 512, 8, 1);
  gemm_h<true, 1><<<8 * 157, 256, 0, stream>>>(H1, wH2, hm_b2, nullptr, H2, QN, 1024, 1024, 8, 1);
  gemm_h<true, 1><<<8 * 157, 256, 0, stream>>>(H2, wH3, hm_b3, nullptr, H3, QN, 1024, 1024, 8, 1);
  gemm_h<false, 2><<<4 * 157, 256, 0, stream>>>(H3, wH4, nullptr, part, nullptr, QN, 128, 1024, 1, 4);
  kreduce_kernel<<<(QN * (CN / 4) + 255) / 256, 256, 0, stream>>>(part, hm_b4, out);
}